// Round 1
// baseline (60.622 us; speedup 1.0000x reference)
//
#include <hip/hip_runtime.h>
#include <math.h>

// Problem constants (fixed by the reference setup_inputs):
//   query:  [B, D]   f32
//   values: [B, T, D] f32
//   out: context [B, D] ++ weights [B, T], f32, concatenated flat.
#define B_ 32
#define T_ 8192
#define D_ 256
#define TTILE 128            // t-rows per block
#define NT (T_ / TTILE)      // 64 tiles per batch
#define NPART (B_ * NT)      // 2048 blocks / partials

// ---------------------------------------------------------------------------
// Pass 1: stream values ONCE. Per block = (b, tile of 128 t-rows):
//   - each wave (4 per block) walks rows t0+wave, t0+wave+4, ...
//   - 64 lanes x float4 cover one 256-float row (coalesced 1KB per row)
//   - dot(q,v) -> butterfly reduce -> raw score (stored via LDS, coalesced)
//   - flash-style online softmax: running m, l, o[4 floats/lane]
//   - waves combined via LDS -> one (m, l, o[256]) partial per block in d_ws
// ---------------------------------------------------------------------------
__global__ __launch_bounds__(256) void attn_pass1(
    const float* __restrict__ q,
    const float* __restrict__ v,
    float* __restrict__ scores_out,   // weights region of d_out (raw scores)
    float* __restrict__ part_m,
    float* __restrict__ part_l,
    float* __restrict__ part_o)
{
    const int blk  = blockIdx.x;
    const int b    = blk / NT;
    const int tile = blk % NT;
    const int t0   = tile * TTILE;
    const int wave = threadIdx.x >> 6;
    const int lane = threadIdx.x & 63;
    const int tid  = threadIdx.x;

    // Per-lane slice of q[b]: 4 consecutive d's.
    const float4 q4 = reinterpret_cast<const float4*>(q + b * D_)[lane];

    float  m = -INFINITY;
    float  l = 0.0f;
    float4 o = make_float4(0.f, 0.f, 0.f, 0.f);

    __shared__ float s_sh[TTILE];
    __shared__ float sm[4], sl[4];
    __shared__ float so[4][D_];

    for (int t = t0 + wave; t < t0 + TTILE; t += 4) {
        const float4 v4 =
            reinterpret_cast<const float4*>(v + ((size_t)b * T_ + t) * D_)[lane];

        // partial dot over this lane's 4 d's
        float p = fmaf(q4.x, v4.x,
                  fmaf(q4.y, v4.y,
                  fmaf(q4.z, v4.z, q4.w * v4.w)));

        // 64-lane butterfly reduce -> full score in every lane
        #pragma unroll
        for (int off = 32; off >= 1; off >>= 1)
            p += __shfl_xor(p, off, 64);

        if (lane == 0) s_sh[t - t0] = p;   // raw score, written coalesced later

        // online softmax update
        const float mnew = fmaxf(m, p);
        const float sc   = __expf(m - mnew);   // exp(-inf)=0 on first iter
        const float w    = __expf(p - mnew);
        l   = fmaf(l, sc, w);
        o.x = fmaf(o.x, sc, w * v4.x);
        o.y = fmaf(o.y, sc, w * v4.y);
        o.z = fmaf(o.z, sc, w * v4.z);
        o.w = fmaf(o.w, sc, w * v4.w);
        m   = mnew;
    }

    // stash per-wave state
    if (lane == 0) { sm[wave] = m; sl[wave] = l; }
    *reinterpret_cast<float4*>(&so[wave][lane * 4]) = o;
    __syncthreads();

    // combine the 4 waves (every thread recomputes the cheap scalars)
    const float M  = fmaxf(fmaxf(sm[0], sm[1]), fmaxf(sm[2], sm[3]));
    const float e0 = __expf(sm[0] - M);
    const float e1 = __expf(sm[1] - M);
    const float e2 = __expf(sm[2] - M);
    const float e3 = __expf(sm[3] - M);

    const float oc = so[0][tid] * e0 + so[1][tid] * e1 +
                     so[2][tid] * e2 + so[3][tid] * e3;
    part_o[(size_t)blk * D_ + tid] = oc;

    if (tid == 0) {
        part_m[blk] = M;
        part_l[blk] = sl[0] * e0 + sl[1] * e1 + sl[2] * e2 + sl[3] * e3;
    }

    // coalesced raw-score store
    if (tid < TTILE)
        scores_out[(size_t)b * T_ + t0 + tid] = s_sh[tid];
}

// ---------------------------------------------------------------------------
// Pass 2: one block per batch b.
//   - reduce 64 partials: global max M, scaled sum L, context o/L
//   - normalize raw scores in place: w = exp(s - M) / L
// ---------------------------------------------------------------------------
__global__ __launch_bounds__(256) void attn_pass2(
    const float* __restrict__ part_m,
    const float* __restrict__ part_l,
    const float* __restrict__ part_o,
    float* __restrict__ ctx,          // [B, D]
    float* __restrict__ wts)          // [B, T] (raw scores in, weights out)
{
    const int b   = blockIdx.x;
    const int tid = threadIdx.x;
    const int base = b * NT;

    __shared__ float sscale[NT];
    __shared__ float red[256];

    // ---- max over NT partials ----
    red[tid] = (tid < NT) ? part_m[base + tid] : -INFINITY;
    __syncthreads();
    #pragma unroll
    for (int s = 128; s >= 1; s >>= 1) {
        if (tid < s) red[tid] = fmaxf(red[tid], red[tid + s]);
        __syncthreads();
    }
    const float M = red[0];
    __syncthreads();

    // ---- scaled sum of l ----
    float lv = 0.0f;
    if (tid < NT) {
        const float sc = __expf(part_m[base + tid] - M);
        sscale[tid] = sc;
        lv = part_l[base + tid] * sc;
    }
    red[tid] = lv;
    __syncthreads();
    #pragma unroll
    for (int s = 128; s >= 1; s >>= 1) {
        if (tid < s) red[tid] += red[tid + s];
        __syncthreads();
    }
    const float invL = 1.0f / red[0];

    // ---- context: o[d] = sum_p part_o[p][d] * scale[p]  (coalesced over d) ----
    float o = 0.0f;
    #pragma unroll 4
    for (int p = 0; p < NT; ++p)
        o = fmaf(part_o[(size_t)(base + p) * D_ + tid], sscale[p], o);
    ctx[b * D_ + tid] = o * invL;

    // ---- normalize weights in place ----
    for (int t = tid; t < T_; t += 256) {
        const size_t idx = (size_t)b * T_ + t;
        wts[idx] = __expf(wts[idx] - M) * invL;
    }
}

extern "C" void kernel_launch(void* const* d_in, const int* in_sizes, int n_in,
                              void* d_out, int out_size, void* d_ws, size_t ws_size,
                              hipStream_t stream)
{
    const float* q = (const float*)d_in[0];   // [B, D]
    const float* v = (const float*)d_in[1];   // [B, T, D]

    float* out = (float*)d_out;
    float* ctx = out;             // [B, D]
    float* wts = out + B_ * D_;   // [B, T]

    // workspace layout: part_m[NPART] | part_l[NPART] | part_o[NPART*D_]
    float* part_m = (float*)d_ws;
    float* part_l = part_m + NPART;
    float* part_o = part_l + NPART;

    attn_pass1<<<NPART, 256, 0, stream>>>(q, v, wts, part_m, part_l, part_o);
    attn_pass2<<<B_, 256, 0, stream>>>(part_m, part_l, part_o, ctx, wts);
}

// Round 2
// 54.962 us; speedup vs baseline: 1.1030x; 1.1030x over previous
//
#include <hip/hip_runtime.h>
#include <math.h>

// query:  [B, D]   f32
// values: [B, T, D] f32
// out: context [B, D] ++ weights [B, T], f32, concatenated flat.
#define B_ 32
#define T_ 8192
#define D_ 256
#define TTILE 128            // t-rows per block
#define NT (T_ / TTILE)      // 64 tiles per batch
#define NPART (B_ * NT)      // 2048 blocks / partials
#define RESC_THR 8.0f        // defer-max threshold (exp bounded by e^8)

// ---------------------------------------------------------------------------
// Pass 1: stream values ONCE.
// Block = (b, tile of 128 rows). 4 waves x 2 half-waves = 8 row-streams.
// Each half-wave (32 lanes x 8 floats) owns one row per iteration:
//   row = t0 + i*8 + (wave*2 + half),  i = 0..15
// Online softmax with deferred rescale (anchor m, trigger at p > m+8).
// ---------------------------------------------------------------------------
__global__ __launch_bounds__(256) void attn_pass1(
    const float* __restrict__ q,
    const float* __restrict__ v,
    float* __restrict__ scores_out,   // weights region of d_out (raw scores)
    float* __restrict__ part_m,
    float* __restrict__ part_l,
    float* __restrict__ part_o)
{
    const int blk  = blockIdx.x;
    const int b    = blk >> 6;        // / NT
    const int tile = blk & (NT - 1);  // % NT
    const int t0   = tile * TTILE;
    const int tid  = threadIdx.x;
    const int wave = tid >> 6;
    const int lane = tid & 63;
    const int half = lane >> 5;       // 0 or 1
    const int hl   = lane & 31;       // lane within half-wave
    const int sid  = wave * 2 + half; // stream id, 0..7

    // q slice: 8 consecutive floats per lane (32 lanes cover D=256)
    const float4* q4p = reinterpret_cast<const float4*>(q + b * D_);
    const float4 q0 = q4p[hl * 2];
    const float4 q1 = q4p[hl * 2 + 1];

    const float* vbase = v + ((size_t)b * T_ + t0 + sid) * D_;

    float  m = -INFINITY;
    float  l = 0.0f;
    float4 o0 = make_float4(0.f, 0.f, 0.f, 0.f);
    float4 o1 = make_float4(0.f, 0.f, 0.f, 0.f);

    __shared__ float s_sh[TTILE];
    __shared__ float sm[8], sl[8];
    __shared__ float so[8][D_];

    // prefetch iteration 0
    float4 a0 = reinterpret_cast<const float4*>(vbase)[hl * 2];
    float4 a1 = reinterpret_cast<const float4*>(vbase)[hl * 2 + 1];

    #pragma unroll 2
    for (int i = 0; i < 16; ++i) {
        // prefetch next row pair (clamped address on last iter; result unused)
        const int inext = (i + 1 < 16) ? (i + 1) : 0;
        const float* vn = vbase + (size_t)inext * 8 * D_;
        const float4 c0 = reinterpret_cast<const float4*>(vn)[hl * 2];
        const float4 c1 = reinterpret_cast<const float4*>(vn)[hl * 2 + 1];

        // partial dot over this lane's 8 d's
        float p = fmaf(q0.x, a0.x, fmaf(q0.y, a0.y,
                  fmaf(q0.z, a0.z, fmaf(q0.w, a0.w,
                  fmaf(q1.x, a1.x, fmaf(q1.y, a1.y,
                  fmaf(q1.z, a1.z, q1.w * a1.w)))))));

        // 5-step butterfly within the 32-lane half (xor offsets stay in-half)
        #pragma unroll
        for (int off = 16; off >= 1; off >>= 1)
            p += __shfl_xor(p, off, 64);

        if (hl == 0) s_sh[i * 8 + sid] = p;   // raw score

        // deferred-rescale online softmax (anchor m)
        if (__any(p > m + RESC_THR)) {
            const float mnew = fmaxf(m, p);
            const float sc   = __expf(m - mnew);   // exp(-inf)=0 first time
            l    *= sc;
            o0.x *= sc; o0.y *= sc; o0.z *= sc; o0.w *= sc;
            o1.x *= sc; o1.y *= sc; o1.z *= sc; o1.w *= sc;
            m = mnew;
        }
        const float w = __expf(p - m);    // bounded by e^RESC_THR
        l += w;
        o0.x = fmaf(w, a0.x, o0.x); o0.y = fmaf(w, a0.y, o0.y);
        o0.z = fmaf(w, a0.z, o0.z); o0.w = fmaf(w, a0.w, o0.w);
        o1.x = fmaf(w, a1.x, o1.x); o1.y = fmaf(w, a1.y, o1.y);
        o1.z = fmaf(w, a1.z, o1.z); o1.w = fmaf(w, a1.w, o1.w);

        a0 = c0; a1 = c1;
    }

    // stash per-stream state
    if (hl == 0) { sm[sid] = m; sl[sid] = l; }
    float4* sop = reinterpret_cast<float4*>(&so[sid][hl * 8]);
    sop[0] = o0;
    sop[1] = o1;
    __syncthreads();

    // combine the 8 streams (every thread recomputes the cheap scalars)
    float M = sm[0];
    #pragma unroll
    for (int s = 1; s < 8; ++s) M = fmaxf(M, sm[s]);

    float es[8];
    #pragma unroll
    for (int s = 0; s < 8; ++s) es[s] = __expf(sm[s] - M);

    float oc = 0.0f;
    #pragma unroll
    for (int s = 0; s < 8; ++s) oc = fmaf(so[s][tid], es[s], oc);
    part_o[(size_t)blk * D_ + tid] = oc;

    if (tid == 0) {
        float L = 0.0f;
        #pragma unroll
        for (int s = 0; s < 8; ++s) L = fmaf(sl[s], es[s], L);
        part_m[blk] = M;
        part_l[blk] = L;
    }

    // coalesced raw-score store
    if (tid < TTILE)
        scores_out[(size_t)b * T_ + t0 + tid] = s_sh[tid];
}

// ---------------------------------------------------------------------------
// Pass 2a: one block per batch b. Reduce 64 partials -> ctx, gM, gInvL.
// ---------------------------------------------------------------------------
__global__ __launch_bounds__(256) void attn_pass2a(
    const float* __restrict__ part_m,
    const float* __restrict__ part_l,
    const float* __restrict__ part_o,
    float* __restrict__ ctx,          // [B, D]
    float* __restrict__ gM,           // [B]
    float* __restrict__ gInvL)        // [B]
{
    const int b    = blockIdx.x;
    const int tid  = threadIdx.x;
    const int base = b * NT;

    __shared__ float sscale[NT];
    __shared__ float red[256];

    // ---- max over NT partial anchors ----
    red[tid] = (tid < NT) ? part_m[base + tid] : -INFINITY;
    __syncthreads();
    #pragma unroll
    for (int s = 128; s >= 1; s >>= 1) {
        if (tid < s) red[tid] = fmaxf(red[tid], red[tid + s]);
        __syncthreads();
    }
    const float M = red[0];
    __syncthreads();

    // ---- scaled sum of l ----
    float lv = 0.0f;
    if (tid < NT) {
        const float sc = __expf(part_m[base + tid] - M);
        sscale[tid] = sc;
        lv = part_l[base + tid] * sc;
    }
    red[tid] = lv;
    __syncthreads();
    #pragma unroll
    for (int s = 128; s >= 1; s >>= 1) {
        if (tid < s) red[tid] += red[tid + s];
        __syncthreads();
    }
    const float invL = 1.0f / red[0];

    // ---- context: coalesced over d ----
    float o = 0.0f;
    #pragma unroll 4
    for (int p = 0; p < NT; ++p)
        o = fmaf(part_o[(size_t)(base + p) * D_ + tid], sscale[p], o);
    ctx[b * D_ + tid] = o * invL;

    if (tid == 0) { gM[b] = M; gInvL[b] = invL; }
}

// ---------------------------------------------------------------------------
// Pass 2b: wide normalize of weights. 256 blocks x 256 threads x float4.
//   blk = b*8 + seg; each block covers 1024 floats of one batch row.
// ---------------------------------------------------------------------------
__global__ __launch_bounds__(256) void attn_pass2b(
    const float* __restrict__ gM,
    const float* __restrict__ gInvL,
    float* __restrict__ wts)          // [B, T] raw scores in, weights out
{
    const int blk = blockIdx.x;
    const int b   = blk >> 3;          // / 8
    const int seg = blk & 7;           // % 8
    const int tid = threadIdx.x;

    const float M    = gM[b];
    const float invL = gInvL[b];

    float4* p = reinterpret_cast<float4*>(wts + (size_t)b * T_) +
                seg * 256 + tid;
    float4 x = *p;
    x.x = __expf(x.x - M) * invL;
    x.y = __expf(x.y - M) * invL;
    x.z = __expf(x.z - M) * invL;
    x.w = __expf(x.w - M) * invL;
    *p = x;
}

extern "C" void kernel_launch(void* const* d_in, const int* in_sizes, int n_in,
                              void* d_out, int out_size, void* d_ws, size_t ws_size,
                              hipStream_t stream)
{
    const float* q = (const float*)d_in[0];   // [B, D]
    const float* v = (const float*)d_in[1];   // [B, T, D]

    float* out = (float*)d_out;
    float* ctx = out;             // [B, D]
    float* wts = out + B_ * D_;   // [B, T]

    // workspace: part_m[NPART] | part_l[NPART] | part_o[NPART*D_] | gM[B] | gInvL[B]
    float* part_m = (float*)d_ws;
    float* part_l = part_m + NPART;
    float* part_o = part_l + NPART;
    float* gM     = part_o + (size_t)NPART * D_;
    float* gInvL  = gM + B_;

    attn_pass1<<<NPART, 256, 0, stream>>>(q, v, wts, part_m, part_l, part_o);
    attn_pass2a<<<B_, 256, 0, stream>>>(part_m, part_l, part_o, ctx, gM, gInvL);
    attn_pass2b<<<B_ * 8, 256, 0, stream>>>(gM, gInvL, wts);
}

// Round 3
// 48.380 us; speedup vs baseline: 1.2530x; 1.1361x over previous
//
#include <hip/hip_runtime.h>
#include <math.h>

// query:  [B, D]   f32
// values: [B, T, D] f32
// out: context [B, D] ++ weights [B, T], f32, concatenated flat.
#define B_ 32
#define T_ 8192
#define D_ 256
#define TTILE 128            // t-rows per block
#define NT (T_ / TTILE)      // 64 tiles per batch
#define NPART (B_ * NT)      // 2048 blocks / partials
#define RESC_THR 8.0f        // defer-max threshold (exp bounded by e^8)

// ---------------------------------------------------------------------------
// Pass 1: stream values ONCE.
// Block = (b, tile of 128 rows). 4 waves x 2 half-waves = 8 row-streams.
// Each half-wave (32 lanes x 8 floats) owns one row per iteration:
//   row = t0 + i*8 + (wave*2 + half),  i = 0..15
// Depth-2 prefetch, pairwise processing (2 independent chains), peeled tail
// (NO wasted wrap-around prefetch -> no HBM over-fetch).
// Online softmax with deferred rescale (anchor m, trigger at p > m+8).
// ---------------------------------------------------------------------------
__global__ __launch_bounds__(256) void attn_pass1(
    const float* __restrict__ q,
    const float* __restrict__ v,
    float* __restrict__ scores_out,   // weights region of d_out (raw scores)
    float* __restrict__ part_m,
    float* __restrict__ part_l,
    float* __restrict__ part_o)
{
    const int blk  = blockIdx.x;
    const int b    = blk >> 6;        // / NT
    const int tile = blk & (NT - 1);  // % NT
    const int t0   = tile * TTILE;
    const int tid  = threadIdx.x;
    const int wave = tid >> 6;
    const int lane = tid & 63;
    const int half = lane >> 5;       // 0 or 1
    const int hl   = lane & 31;       // lane within half-wave
    const int sid  = wave * 2 + half; // stream id, 0..7

    // q slice: 8 consecutive floats per lane (32 lanes cover D=256)
    const float4* q4p = reinterpret_cast<const float4*>(q + b * D_);
    const float4 q0 = q4p[hl * 2];
    const float4 q1 = q4p[hl * 2 + 1];

    const float* vbase = v + ((size_t)b * T_ + t0 + sid) * D_;

    float  m = -INFINITY;
    float  l = 0.0f;
    float4 o0 = make_float4(0.f, 0.f, 0.f, 0.f);
    float4 o1 = make_float4(0.f, 0.f, 0.f, 0.f);

    __shared__ float s_sh[TTILE];
    __shared__ float sm[8], sl[8];
    __shared__ float so[8][D_];

    // row-pair loader: iteration i covers rows t0 + i*8 + sid
    auto ld = [&](int i, float4& x0, float4& x1) {
        const float4* p =
            reinterpret_cast<const float4*>(vbase + (size_t)i * 8 * D_);
        x0 = p[hl * 2];
        x1 = p[hl * 2 + 1];
    };

    // score + online-softmax update for one row
    auto proc = [&](int i, const float4& a0, const float4& a1) {
        float p = fmaf(q0.x, a0.x, fmaf(q0.y, a0.y,
                  fmaf(q0.z, a0.z, fmaf(q0.w, a0.w,
                  fmaf(q1.x, a1.x, fmaf(q1.y, a1.y,
                  fmaf(q1.z, a1.z, q1.w * a1.w)))))));

        // 5-step butterfly within the 32-lane half
        #pragma unroll
        for (int off = 16; off >= 1; off >>= 1)
            p += __shfl_xor(p, off, 64);

        if (hl == 0) s_sh[i * 8 + sid] = p;   // raw score

        // deferred-rescale online softmax (anchor m)
        if (__any(p > m + RESC_THR)) {
            const float mnew = fmaxf(m, p);
            const float sc   = __expf(m - mnew);   // exp(-inf)=0 first time
            l    *= sc;
            o0.x *= sc; o0.y *= sc; o0.z *= sc; o0.w *= sc;
            o1.x *= sc; o1.y *= sc; o1.z *= sc; o1.w *= sc;
            m = mnew;
        }
        const float w = __expf(p - m);    // bounded by e^RESC_THR
        l += w;
        o0.x = fmaf(w, a0.x, o0.x); o0.y = fmaf(w, a0.y, o0.y);
        o0.z = fmaf(w, a0.z, o0.z); o0.w = fmaf(w, a0.w, o0.w);
        o1.x = fmaf(w, a1.x, o1.x); o1.y = fmaf(w, a1.y, o1.y);
        o1.z = fmaf(w, a1.z, o1.z); o1.w = fmaf(w, a1.w, o1.w);
    };

    float4 A0, A1, B0, B1;
    ld(0, A0, A1);
    ld(1, B0, B1);

    #pragma unroll
    for (int i = 0; i < 16; i += 2) {
        float4 C0, C1, E0, E1;
        if (i + 2 < 16) ld(i + 2, C0, C1);
        if (i + 3 < 16) ld(i + 3, E0, E1);
        proc(i,     A0, A1);
        proc(i + 1, B0, B1);
        if (i + 2 < 16) { A0 = C0; A1 = C1; }
        if (i + 3 < 16) { B0 = E0; B1 = E1; }
    }

    // stash per-stream state
    if (hl == 0) { sm[sid] = m; sl[sid] = l; }
    float4* sop = reinterpret_cast<float4*>(&so[sid][hl * 8]);
    sop[0] = o0;
    sop[1] = o1;
    __syncthreads();

    // combine the 8 streams (every thread recomputes the cheap scalars)
    float M = sm[0];
    #pragma unroll
    for (int s = 1; s < 8; ++s) M = fmaxf(M, sm[s]);

    float es[8];
    #pragma unroll
    for (int s = 0; s < 8; ++s) es[s] = __expf(sm[s] - M);

    float oc = 0.0f;
    #pragma unroll
    for (int s = 0; s < 8; ++s) oc = fmaf(so[s][tid], es[s], oc);
    part_o[(size_t)blk * D_ + tid] = oc;

    if (tid == 0) {
        float L = 0.0f;
        #pragma unroll
        for (int s = 0; s < 8; ++s) L = fmaf(sl[s], es[s], L);
        part_m[blk] = M;
        part_l[blk] = L;
    }

    // coalesced raw-score store
    if (tid < TTILE)
        scores_out[(size_t)b * T_ + t0 + tid] = s_sh[tid];
}

// ---------------------------------------------------------------------------
// Pass 2 (fused): one 1024-thread block per batch b.
//   wave 0:    butterfly-reduce 64 partial (m,l) -> M, invL
//   4 groups:  16 partials each -> ctx (4x parallel reduction)
//   all 1024:  normalize 8192 raw scores (2 x float4 per thread)
// ---------------------------------------------------------------------------
__global__ __launch_bounds__(1024) void attn_pass2(
    const float* __restrict__ part_m,
    const float* __restrict__ part_l,
    const float* __restrict__ part_o,
    float* __restrict__ ctx,          // [B, D]
    float* __restrict__ wts)          // [B, T] raw scores in, weights out
{
    const int b    = blockIdx.x;
    const int tid  = threadIdx.x;
    const int base = b * NT;          // NT = 64

    __shared__ float sscale[NT];
    __shared__ float sML[2];
    __shared__ float octx[4][D_];

    // ---- wave 0: M and invL via 64-lane butterflies ----
    if (tid < 64) {
        const float mv = part_m[base + tid];
        float M = mv;
        #pragma unroll
        for (int off = 32; off >= 1; off >>= 1)
            M = fmaxf(M, __shfl_xor(M, off, 64));

        const float sc = __expf(mv - M);
        sscale[tid] = sc;

        float lv = part_l[base + tid] * sc;
        #pragma unroll
        for (int off = 32; off >= 1; off >>= 1)
            lv += __shfl_xor(lv, off, 64);

        if (tid == 0) { sML[0] = M; sML[1] = 1.0f / lv; }
    }
    __syncthreads();
    const float M    = sML[0];
    const float invL = sML[1];

    // ---- ctx: 4 groups x 16 partials, coalesced over d ----
    const int grp = tid >> 8;   // 0..3
    const int d   = tid & 255;
    float o = 0.0f;
    #pragma unroll
    for (int p = 0; p < 16; ++p) {
        const int pi = grp * 16 + p;
        o = fmaf(part_o[(size_t)(base + pi) * D_ + d], sscale[pi], o);
    }
    octx[grp][d] = o;
    __syncthreads();
    if (tid < D_)
        ctx[b * D_ + tid] =
            (octx[0][tid] + octx[1][tid] + octx[2][tid] + octx[3][tid]) * invL;

    // ---- normalize weights: 1024 threads x float4 x 2 ----
    float4* wp = reinterpret_cast<float4*>(wts + (size_t)b * T_);
    #pragma unroll
    for (int it = 0; it < 2; ++it) {
        float4 x = wp[it * 1024 + tid];
        x.x = __expf(x.x - M) * invL;
        x.y = __expf(x.y - M) * invL;
        x.z = __expf(x.z - M) * invL;
        x.w = __expf(x.w - M) * invL;
        wp[it * 1024 + tid] = x;
    }
}

extern "C" void kernel_launch(void* const* d_in, const int* in_sizes, int n_in,
                              void* d_out, int out_size, void* d_ws, size_t ws_size,
                              hipStream_t stream)
{
    const float* q = (const float*)d_in[0];   // [B, D]
    const float* v = (const float*)d_in[1];   // [B, T, D]

    float* out = (float*)d_out;
    float* ctx = out;             // [B, D]
    float* wts = out + B_ * D_;   // [B, T]

    // workspace: part_m[NPART] | part_l[NPART] | part_o[NPART*D_]
    float* part_m = (float*)d_ws;
    float* part_l = part_m + NPART;
    float* part_o = part_l + NPART;

    attn_pass1<<<NPART, 256, 0, stream>>>(q, v, wts, part_m, part_l, part_o);
    attn_pass2<<<B_, 1024, 0, stream>>>(part_m, part_l, part_o, ctx, wts);
}